// Round 5
// baseline (11508.694 us; speedup 1.0000x reference)
//
#include <hip/hip_runtime.h>
#include <hip/hip_bf16.h>

#define D_   256
#define NH_  8
#define NL_  4
#define NP_  4
#define DFF_ 1024
#define BS_  8
#define NQ_  900
#define HD_  32
#define LS_  13294

static const int NE   = BS_ * NQ_ * D_;   // 1,843,200
static const int NEb  = NQ_ * D_;         //   230,400
static const int AWb  = NQ_ * 128;        //   115,200

typedef __hip_bfloat16 bf16;

__device__ __forceinline__ float to_f(bf16 x) { return __bfloat162float(x); }
__device__ __forceinline__ float ld(const void* p, size_t i, int f32) {
    return f32 ? ((const float*)p)[i] : __bfloat162float(((const bf16*)p)[i]);
}
__device__ __forceinline__ void st_out(void* p, size_t i, int f32, float v) {
    if (f32) ((float*)p)[i] = v;
    else ((bf16*)p)[i] = __float2bfloat16(v);
}

// ---------------------------------------------------------------- dtype probe
__global__ __launch_bounds__(256) void probe_kernel(const unsigned short* __restrict__ t,
                                                    int* __restrict__ flag) {
    __shared__ int c;
    if (threadIdx.x == 0) c = 0;
    __syncthreads();
    unsigned short v = t[2 * threadIdx.x];   // even bf16-view slots
    int e = (v >> 7) & 0xFF;
    if (e < 90 || e > 140) atomicAdd(&c, 1); // implausible exponent for N(0,1)
    __syncthreads();
    if (threadIdx.x == 0) flag[0] = (c > 64) ? 1 : 0;  // 1 => storage is f32
}

// ---------------------------------------------------------------- prep: qps = tgt + qpos
__global__ __launch_bounds__(256) void prep_kernel(const void* __restrict__ tgt,
                                                   const void* __restrict__ qpos,
                                                   size_t ebase,
                                                   bf16* __restrict__ qps,
                                                   const int* __restrict__ flag) {
    int f = *flag;
    int e = blockIdx.x * 256 + threadIdx.x;
    qps[e] = __float2bfloat16(ld(tgt, ebase + e, f) + ld(qpos, ebase + e, f));
}

// ---------------------------------------------------------------- GEMM: C[M,N] = A[M,K] @ W[N,K]^T + bias
// a_dyn: 0 = A ws bf16; 1 = A external flag-typed; 2 = A ws f32.  aeb = element base for A.
template <bool RELU>
__global__ __launch_bounds__(256) void gemm_kernel(const void* __restrict__ A, int a_dyn, size_t aeb,
                                                   const void* __restrict__ W,
                                                   const void* __restrict__ bias,
                                                   void* __restrict__ C, int c_f32,
                                                   int M, int N, int K,
                                                   const int* __restrict__ flag) {
    __shared__ float As[16][65];
    __shared__ float Ws[16][65];
    int f = *flag;
    int a_f32 = (a_dyn == 2) || (a_dyn == 1 && f);
    int tid = threadIdx.x;
    int tx = tid & 15, ty = tid >> 4;
    int row0 = blockIdx.y * 64, col0 = blockIdx.x * 64;
    float acc[4][4] = {};
    for (int k0 = 0; k0 < K; k0 += 16) {
#pragma unroll
        for (int t = 0; t < 4; t++) {
            int e = tid + t * 256;
            int m = e >> 4, kk = e & 15;
            int gr = row0 + m;
            As[kk][m] = (gr < M) ? ld(A, aeb + (size_t)gr * K + k0 + kk, a_f32) : 0.f;
            int gc = col0 + m;  // N multiple of 64
            Ws[kk][m] = ld(W, (size_t)gc * K + k0 + kk, f);
        }
        __syncthreads();
#pragma unroll
        for (int kk = 0; kk < 16; kk++) {
            float a[4], b[4];
#pragma unroll
            for (int i = 0; i < 4; i++) a[i] = As[kk][ty + 16 * i];
#pragma unroll
            for (int j = 0; j < 4; j++) b[j] = Ws[kk][tx + 16 * j];
#pragma unroll
            for (int i = 0; i < 4; i++)
#pragma unroll
                for (int j = 0; j < 4; j++) acc[i][j] += a[i] * b[j];
        }
        __syncthreads();
    }
#pragma unroll
    for (int i = 0; i < 4; i++) {
        int r = row0 + ty + 16 * i;
        if (r >= M) continue;
#pragma unroll
        for (int j = 0; j < 4; j++) {
            int c = col0 + tx + 16 * j;
            float v = acc[i][j] + ld(bias, c, f);
            if (RELU) v = fmaxf(v, 0.f);
            if (c_f32) ((float*)C)[(size_t)r * N + c] = v;
            else ((bf16*)C)[(size_t)r * N + c] = __float2bfloat16(v);
        }
    }
}

// ---------------------------------------------------------------- attention (ws bf16; one wave per (h,query))
template <int HD>
__global__ __launch_bounds__(64) void attn_kernel(const bf16* __restrict__ Q,
                                                  const bf16* __restrict__ K,
                                                  const bf16* __restrict__ V,
                                                  bf16* __restrict__ O,
                                                  int H, int L, float scale) {
    int bid = blockIdx.x;
    int i = bid % L;
    int h = bid / L;
    const int dm = H * HD;
    __shared__ float qs[HD];
    __shared__ float ps[64];
    int lane = threadIdx.x;
    const bf16* qp = Q + (size_t)i * dm + h * HD;
    if (lane < HD) qs[lane] = to_f(qp[lane]);
    __syncthreads();

    float m = -1e30f, s = 0.f;
    for (int j = lane; j < L; j += 64) {
        const bf16* kp = K + (size_t)j * dm + h * HD;
        float dot = 0.f;
#pragma unroll
        for (int d = 0; d < HD; d++) dot += qs[d] * to_f(kp[d]);
        dot *= scale;
        float mn = fmaxf(m, dot);
        s = s * __expf(m - mn) + __expf(dot - mn);
        m = mn;
    }
#pragma unroll
    for (int o = 32; o; o >>= 1) {
        float m2 = __shfl_xor(m, o);
        float s2 = __shfl_xor(s, o);
        float mn = fmaxf(m, m2);
        s = s * __expf(m - mn) + s2 * __expf(m2 - mn);
        m = mn;
    }
    float inv_s = 1.f / s;

    float acc = 0.f;
    for (int j0 = 0; j0 < L; j0 += 64) {
        int j = j0 + lane;
        float p = 0.f;
        if (j < L) {
            const bf16* kp = K + (size_t)j * dm + h * HD;
            float dot = 0.f;
#pragma unroll
            for (int d = 0; d < HD; d++) dot += qs[d] * to_f(kp[d]);
            p = __expf(dot * scale - m);
        }
        __syncthreads();
        ps[lane] = p;
        __syncthreads();
        if (lane < HD) {
            int jend = min(64, L - j0);
            const bf16* vp = V + (size_t)j0 * dm + h * HD + lane;
            for (int jj = 0; jj < jend; jj++) acc += ps[jj] * to_f(vp[(size_t)jj * dm]);
        }
    }
    if (lane < HD) O[(size_t)i * dm + h * HD + lane] = __float2bfloat16(acc * inv_s);
}

// ---------------------------------------------------------------- pairing
__global__ __launch_bounds__(64) void find_second_kernel(const void* __restrict__ gious,
                                                         const void* __restrict__ cxcys,
                                                         size_t ebase,
                                                         int* __restrict__ second,
                                                         int* __restrict__ sel,
                                                         const int* __restrict__ flag) {
    int f = *flag;
    int i = blockIdx.x;
    int lane = threadIdx.x;
    float best = -1e30f;
    int bidx = 1 << 30;
    for (int j = lane; j < NQ_; j += 64) {
        if (j == i) continue;
        float v = ld(gious, ebase + (size_t)i * NQ_ + j, f);
        if (v > best) { best = v; bidx = j; }
    }
#pragma unroll
    for (int o = 32; o; o >>= 1) {
        float v2 = __shfl_xor(best, o);
        int i2 = __shfl_xor(bidx, o);
        if (v2 > best || (v2 == best && i2 < bidx)) { best = v2; bidx = i2; }
    }
    if (lane == 0) {
        second[i] = bidx;
        float c = ld(cxcys, ebase + (size_t)i * NQ_ + bidx, f);
        sel[i] = (c == 0.f) ? 1 : 0;
    }
}

__global__ __launch_bounds__(256) void build_pair_kernel(const bf16* __restrict__ X,
                                                         const bf16* __restrict__ Y,
                                                         const int* __restrict__ second,
                                                         const int* __restrict__ sel,
                                                         bf16* __restrict__ out2) {
    int e = blockIdx.x * 256 + threadIdx.x;  // < NEb
    int d = e & 255;
    int i = e >> 8;
    int s = sel[i];
    int j = second[i];
    bf16 a = X[(size_t)i * 256 + d];
    bf16 c = Y[(size_t)j * 256 + d];
    size_t o = (size_t)i * 512 + d;
    out2[o]       = s ? a : c;
    out2[o + 256] = s ? c : a;
}

// ---------------------------------------------------------------- block reduction (256 threads)
__device__ __forceinline__ float block_sum_256(float v, float* sm) {
#pragma unroll
    for (int o = 32; o; o >>= 1) v += __shfl_down(v, o);
    int w = threadIdx.x >> 6, lane = threadIdx.x & 63;
    if (lane == 0) sm[w] = v;
    __syncthreads();
    float r = sm[0] + sm[1] + sm[2] + sm[3];
    __syncthreads();
    return r;
}

__global__ __launch_bounds__(256) void ln_pair_kernel(const void* __restrict__ tgt,
                                                      const void* __restrict__ qpos,
                                                      size_t ebase,
                                                      const bf16* __restrict__ tgt2,
                                                      const bf16* __restrict__ tgt3full,
                                                      const int* __restrict__ sel,
                                                      const void* __restrict__ g1, const void* __restrict__ b1,
                                                      const void* __restrict__ g12, const void* __restrict__ b12,
                                                      float* __restrict__ xbuf,
                                                      bf16* __restrict__ query_d,
                                                      const int* __restrict__ flag) {
    __shared__ float sm[4];
    int f = *flag;
    int i = blockIdx.x, d = threadIdx.x;
    size_t base = (size_t)i * 256;
    float t = ld(tgt, ebase + base + d, f);
    float a1 = t + to_f(tgt2[base + d]);
    int s = sel[i];
    float t3 = to_f(tgt3full[(size_t)i * 512 + (s ? 0 : 256) + d]);
    float a2 = t + t3;
    float m1 = block_sum_256(a1, sm) * (1.f / 256.f);
    float m2 = block_sum_256(a2, sm) * (1.f / 256.f);
    float d1 = a1 - m1, d2 = a2 - m2;
    float v1 = block_sum_256(d1 * d1, sm) * (1.f / 256.f);
    float v2 = block_sum_256(d2 * d2, sm) * (1.f / 256.f);
    float o1 = d1 * rsqrtf(v1 + 1e-5f) * ld(g1, d, f) + ld(b1, d, f);
    float o2 = d2 * rsqrtf(v2 + 1e-5f) * ld(g12, d, f) + ld(b12, d, f);
    float xv = o1 + o2;
    xbuf[base + d] = xv;
    query_d[base + d] = __float2bfloat16(xv + ld(qpos, ebase + base + d, f));
}

// out_mode: 1 = ws f32 (oeb=0), 0 = d_out flag-typed at element base oeb
__global__ __launch_bounds__(256) void ln_add_kernel(const float* __restrict__ A,
                                                     const bf16* __restrict__ Badd,
                                                     const void* __restrict__ g, const void* __restrict__ be,
                                                     void* __restrict__ out, int out_mode, size_t oeb,
                                                     const int* __restrict__ flag) {
    __shared__ float sm[4];
    int f = *flag;
    int i = blockIdx.x, d = threadIdx.x;
    size_t base = (size_t)i * 256;
    float v = A[base + d] + to_f(Badd[base + d]);
    float m = block_sum_256(v, sm) * (1.f / 256.f);
    float dv = v - m;
    float var = block_sum_256(dv * dv, sm) * (1.f / 256.f);
    float o = dv * rsqrtf(var + 1e-5f) * ld(g, d, f) + ld(be, d, f);
    if (out_mode == 1) ((float*)out)[base + d] = o;
    else st_out(out, oeb + base + d, f, o);
}

// ---------------------------------------------------------------- deformable attention pieces
__global__ __launch_bounds__(128) void aw_softmax_kernel(float* __restrict__ aw,
                                                         void* __restrict__ out_aw, size_t oeb,
                                                         const int* __restrict__ flag) {
    int f = *flag;
    int i = blockIdx.x, t = threadIdx.x;
    size_t idx = (size_t)i * 128 + t;
    float v = aw[idx];
    float mx = v;
#pragma unroll
    for (int o = 8; o; o >>= 1) mx = fmaxf(mx, __shfl_xor(mx, o, 16));
    float e = __expf(v - mx);
    float s = e;
#pragma unroll
    for (int o = 8; o; o >>= 1) s += __shfl_xor(s, o, 16);
    float r = e / s;
    aw[idx] = r;
    st_out(out_aw, oeb + idx, f, r);
}

__global__ __launch_bounds__(256) void loc_kernel(const void* __restrict__ refp, size_t rbase,
                                                  const bf16* __restrict__ off,
                                                  float* __restrict__ locbuf,
                                                  void* __restrict__ out_loc, size_t oeb,
                                                  const int* __restrict__ flag) {
    int f = *flag;
    int e = blockIdx.x * 256 + threadIdx.x;  // [NQ,H,L,P,2]
    int c = e & 1;
    int l = (e >> 3) & 3;
    int i = e >> 8;
    const float norm[4] = {100.f, 50.f, 25.f, 13.f};  // W == H per level
    float rv = ld(refp, rbase + ((size_t)i * 4 + l) * 2 + c, f);
    float lv = rv + to_f(off[e]) / norm[l];
    locbuf[e] = lv;
    st_out(out_loc, oeb + e, f, lv);
}

// Fused bilinear-sample + value-projection + attention-weighting.
// Uses linearity: bilinear(src@vw^T + vb) = bilinear(src)@vw^T + (sum valid w)*vb,
// and folds aw first: G[h] = sum_{l,p} aw * bilinear_src  (8x256 in LDS),
// samp[q, h*32+d] = G[h] . vw_row(h*32+d) + bscale[h]*vb.
__global__ __launch_bounds__(256) void deform_fused_kernel(const void* __restrict__ src, size_t sbase,
                                                           const void* __restrict__ vw,
                                                           const void* __restrict__ vb,
                                                           const float* __restrict__ locb,
                                                           const float* __restrict__ awb,
                                                           float* __restrict__ samp,
                                                           const int* __restrict__ flag) {
    int f = *flag;
    int q = blockIdx.x;
    int t = threadIdx.x;
    __shared__ float G[8][257];
    __shared__ int   rowi[128][4];
    __shared__ float wc[128][4];
    __shared__ float wv_s[128];
    __shared__ float aw_s[128];
#pragma unroll
    for (int h = 0; h < 8; h++) G[h][t] = 0.f;
    if (t < 128) {
        const int HW[4] = {100, 50, 25, 13};
        const int ST[4] = {0, 10000, 12500, 13125};
        int le = t;                       // h*16 + l*4 + p
        int l = (le >> 2) & 3;
        int W = HW[l], H = W, st = ST[l];
        float lx = locb[(size_t)q * 256 + le * 2];
        float ly = locb[(size_t)q * 256 + le * 2 + 1];
        float x = lx * W - 0.5f, y = ly * H - 0.5f;
        float xf = floorf(x), yf = floorf(y);
        int x0 = (int)xf, y0 = (int)yf;
        float wx1 = x - xf, wy1 = y - yf;
        float wx0 = 1.f - wx1, wy0 = 1.f - wy1;
        bool xv0 = (x0 >= 0) && (x0 < W), xv1 = (x0 + 1 >= 0) && (x0 + 1 < W);
        bool yv0 = (y0 >= 0) && (y0 < H), yv1 = (y0 + 1 >= 0) && (y0 + 1 < H);
        int cx0 = min(max(x0, 0), W - 1), cx1 = min(max(x0 + 1, 0), W - 1);
        int cy0 = min(max(y0, 0), H - 1), cy1 = min(max(y0 + 1, 0), H - 1);
        rowi[le][0] = st + cy0 * W + cx0;  wc[le][0] = (xv0 && yv0) ? wx0 * wy0 : 0.f;
        rowi[le][1] = st + cy0 * W + cx1;  wc[le][1] = (xv1 && yv0) ? wx1 * wy0 : 0.f;
        rowi[le][2] = st + cy1 * W + cx0;  wc[le][2] = (xv0 && yv1) ? wx0 * wy1 : 0.f;
        rowi[le][3] = st + cy1 * W + cx1;  wc[le][3] = (xv1 && yv1) ? wx1 * wy1 : 0.f;
        wv_s[le] = wc[le][0] + wc[le][1] + wc[le][2] + wc[le][3];
        aw_s[le] = awb[(size_t)q * 128 + le];
    }
    __syncthreads();
    for (int le = 0; le < 128; le++) {
        float a = aw_s[le];
        float w0 = wc[le][0], w1 = wc[le][1], w2 = wc[le][2], w3 = wc[le][3];
        float v = 0.f;
        if (w0 != 0.f) v += w0 * ld(src, sbase + (size_t)rowi[le][0] * 256 + t, f);
        if (w1 != 0.f) v += w1 * ld(src, sbase + (size_t)rowi[le][1] * 256 + t, f);
        if (w2 != 0.f) v += w2 * ld(src, sbase + (size_t)rowi[le][2] * 256 + t, f);
        if (w3 != 0.f) v += w3 * ld(src, sbase + (size_t)rowi[le][3] * 256 + t, f);
        G[le >> 4][t] += a * v;
    }
    __syncthreads();
    int c = t, h = c >> 5;
    float bscale = 0.f;
#pragma unroll
    for (int r = 0; r < 16; r++) bscale += aw_s[h * 16 + r] * wv_s[h * 16 + r];
    float acc = bscale * ld(vb, c, f);
    for (int k = 0; k < 256; k++) acc += G[h][k] * ld(vw, (size_t)c * 256 + k, f);
    samp[(size_t)q * 256 + c] = acc;
}

// ================================================================ launch
extern "C" void kernel_launch(void* const* d_in, const int* in_sizes, int n_in,
                              void* d_out, int out_size, void* d_ws, size_t ws_size,
                              hipStream_t stream) {
    (void)in_sizes; (void)n_in; (void)out_size; (void)ws_size;
    void* out = d_out;

    // -------- ws layout: total 6,920,448 B
    char* base = (char*)d_ws;
    int*   flag   = (int*)base;                         // 256 B
    float* xbuf   = (float*)(base + 256);               // NEb f32   921,600 B
    bf16*  query  = (bf16*)(base + 256 + 921600);       // NEb bf16  460,800 B
    bf16*  qps    = (bf16*)(base + 256 + 1382400);      // NEb bf16
    bf16*  tgt2   = (bf16*)(base + 256 + 1843200);      // NEb bf16
    int*   second = (int*)(base + 256 + 2304000);       // 3,600 B
    int*   sel    = second + NQ_;                       // 3,600 B
    char*  A      = base + 2312448;                     // arena, peak 4,608,000 B

    const dim3 blk256(256);
    const int gyb = (NQ_ + 63) / 64;   // 15

    probe_kernel<<<1, blk256, 0, stream>>>((const unsigned short*)d_in[0], flag);

    for (int b = 0; b < BS_; b++) {
        const size_t o_tgt  = (size_t)b * NEb;
        const size_t o_refp = (size_t)b * NQ_ * 8;
        const size_t o_src  = (size_t)b * LS_ * 256;
        const size_t o_gc   = (size_t)b * NQ_ * NQ_;
        const size_t o_outx = (size_t)b * NEb;
        const size_t o_loc  = (size_t)NE + (size_t)b * NEb;
        const size_t o_aw   = (size_t)2 * NE + (size_t)b * AWb;

        // ---- stage A (arena: 4 x 460,800 B)
        bf16* Q1   = (bf16*)A;
        bf16* K1   = (bf16*)(A + 460800);
        bf16* V1   = (bf16*)(A + 921600);
        bf16* att1 = (bf16*)(A + 1382400);
        prep_kernel<<<NEb / 256, blk256, 0, stream>>>(d_in[0], d_in[1], o_tgt, qps, flag);
        gemm_kernel<false><<<dim3(4, gyb), blk256, 0, stream>>>(qps, 0, 0, d_in[8], d_in[9], Q1, 0, NQ_, 256, 256, flag);
        gemm_kernel<false><<<dim3(4, gyb), blk256, 0, stream>>>(qps, 0, 0, d_in[10], d_in[11], K1, 0, NQ_, 256, 256, flag);
        gemm_kernel<false><<<dim3(4, gyb), blk256, 0, stream>>>(d_in[0], 1, o_tgt, d_in[12], d_in[13], V1, 0, NQ_, 256, 256, flag);
        attn_kernel<32><<<NH_ * NQ_, 64, 0, stream>>>(Q1, K1, V1, att1, NH_, NQ_, 0.17677669529663687f);
        gemm_kernel<false><<<dim3(4, gyb), blk256, 0, stream>>>(att1, 0, 0, d_in[14], d_in[15], tgt2, 0, NQ_, 256, 256, flag);

        // ---- stage B (arena: 4 x 921,600 B = 3,686,400)
        bf16* pairX = (bf16*)A;               // then att2
        bf16* Q2    = (bf16*)(A + 921600);    // then tgt3
        bf16* K2    = (bf16*)(A + 1843200);
        bf16* V2    = (bf16*)(A + 2764800);
        find_second_kernel<<<NQ_, 64, 0, stream>>>(d_in[7], d_in[6], o_gc, second, sel, flag);
        build_pair_kernel<<<NQ_, blk256, 0, stream>>>(qps, qps, second, sel, pairX);
        gemm_kernel<false><<<dim3(8, gyb), blk256, 0, stream>>>(pairX, 0, 0, d_in[16], d_in[17], Q2, 0, NQ_, 512, 512, flag);
        build_pair_kernel<<<NQ_, blk256, 0, stream>>>(qps, tgt2, second, sel, pairX);
        gemm_kernel<false><<<dim3(8, gyb), blk256, 0, stream>>>(pairX, 0, 0, d_in[18], d_in[19], K2, 0, NQ_, 512, 512, flag);
        build_pair_kernel<<<NQ_, blk256, 0, stream>>>(tgt2, tgt2, second, sel, pairX);
        gemm_kernel<false><<<dim3(8, gyb), blk256, 0, stream>>>(pairX, 0, 0, d_in[20], d_in[21], V2, 0, NQ_, 512, 512, flag);
        attn_kernel<64><<<NH_ * NQ_, 64, 0, stream>>>(Q2, K2, V2, pairX, NH_, NQ_, 0.125f);
        gemm_kernel<false><<<dim3(8, gyb), blk256, 0, stream>>>(pairX, 0, 0, d_in[22], d_in[23], Q2, 0, NQ_, 512, 512, flag);

        ln_pair_kernel<<<NQ_, blk256, 0, stream>>>(d_in[0], d_in[1], o_tgt, tgt2, Q2, sel,
                                                   d_in[32], d_in[33], d_in[34], d_in[35], xbuf, query, flag);

        // ---- stage C (arena: offb | awb | locb | samp = 2,764,800 B)
        bf16*  offb = (bf16*)A;                       //   460,800 B
        float* awb  = (float*)(A + 460800);           //   460,800 B
        float* locb = (float*)(A + 921600);           //   921,600 B
        float* samp = (float*)(A + 1843200);          //   921,600 B (lives into stage D)
        gemm_kernel<false><<<dim3(4, gyb), blk256, 0, stream>>>(query, 0, 0, d_in[26], d_in[27], offb, 0, NQ_, 256, 256, flag);
        gemm_kernel<false><<<dim3(2, gyb), blk256, 0, stream>>>(query, 0, 0, d_in[28], d_in[29], awb, 1, NQ_, 128, 256, flag);
        aw_softmax_kernel<<<NQ_, 128, 0, stream>>>(awb, out, o_aw, flag);
        loc_kernel<<<NQ_, blk256, 0, stream>>>(d_in[2], o_refp, offb, locb, out, o_loc, flag);
        deform_fused_kernel<<<NQ_, blk256, 0, stream>>>(d_in[3], o_src, d_in[24], d_in[25], locb, awb, samp, flag);

        // ---- stage D (ca | x2 | ffn | [samp] | h1; peak arena 4,608,000 B)
        bf16*  ca  = (bf16*)A;                        //   460,800 B
        float* x2  = (float*)(A + 460800);            //   921,600 B (offb/awb/locb dead)
        bf16*  ffn = (bf16*)(A + 1382400);            //   460,800 B
        bf16*  h1  = (bf16*)(A + 2764800);            // 1,843,200 B (after samp)
        gemm_kernel<false><<<dim3(4, gyb), blk256, 0, stream>>>(samp, 2, 0, d_in[30], d_in[31], ca, 0, NQ_, 256, 256, flag);
        ln_add_kernel<<<NQ_, blk256, 0, stream>>>(xbuf, ca, d_in[32], d_in[33], x2, 1, 0, flag);
        gemm_kernel<true><<<dim3(16, gyb), blk256, 0, stream>>>(x2, 2, 0, d_in[38], d_in[39], h1, 0, NQ_, 1024, 256, flag);
        gemm_kernel<false><<<dim3(4, gyb), blk256, 0, stream>>>(h1, 0, 0, d_in[40], d_in[41], ffn, 0, NQ_, 256, 1024, flag);
        ln_add_kernel<<<NQ_, blk256, 0, stream>>>(x2, ffn, d_in[36], d_in[37], out, 0, o_outx, flag);
    }
}